// Round 1
// baseline (26031.470 us; speedup 1.0000x reference)
//
#include <hip/hip_runtime.h>

#define OBS_STRIDE 490

// ---------------------------------------------------------------------------
// K1: preprocess (grid build + unit scatter) + conv1/2/3 + 4x4 avg pool.
// One block per batch element, 1024 threads (4 "quarters" x 256 positions).
// Single LDS buffer A[64][256] (64KB) ping-pongs activations:
//   rows 0..8 : 9-channel input grid
//   rows 32..63: act1 (32 ch) after conv1
//   rows 0..63 : act2 (64 ch) after conv2 (reg-compute then overwrite)
//   rows 0..63 : act3 (64 ch) after conv3 (reg-compute then overwrite)
// ---------------------------------------------------------------------------

__device__ __forceinline__ void load_win(const float* __restrict__ rp, int p,
                                         bool bN, bool bS, bool bW, bool bE,
                                         float* win) {
    win[0] = (bN && bW) ? rp[p - 17] : 0.f;
    win[1] = bN         ? rp[p - 16] : 0.f;
    win[2] = (bN && bE) ? rp[p - 15] : 0.f;
    win[3] = bW         ? rp[p - 1]  : 0.f;
    win[4] =              rp[p];
    win[5] = bE         ? rp[p + 1]  : 0.f;
    win[6] = (bS && bW) ? rp[p + 15] : 0.f;
    win[7] = bS         ? rp[p + 16] : 0.f;
    win[8] = (bS && bE) ? rp[p + 17] : 0.f;
}

__global__ __launch_bounds__(1024) void conv_kernel(
    const float* __restrict__ obs,
    const float* __restrict__ w1, const float* __restrict__ b1,
    const float* __restrict__ w2, const float* __restrict__ b2,
    const float* __restrict__ w3, const float* __restrict__ b3,
    float* __restrict__ pooled)
{
    __shared__ float A[64][256];

    const int tid = threadIdx.x;
    const int b   = blockIdx.x;
    const float* ob = obs + (size_t)b * OBS_STRIDE;

    // phase 0: terrain into ch0, zero ch1..8
    for (int i = tid; i < 9 * 256; i += 1024) {
        int ch = i >> 8, p = i & 255;
        A[ch][p] = (ch == 0) ? ob[p] : 0.f;
    }
    __syncthreads();

    // phase 1: unit scatter (20 units). Replicates reference fp32 index math.
    if (tid < 20) {
        const float* up = ob + 256 + tid * 10;
        float team = up[1], rf = up[2], cf = up[3];
        float hp = up[4], mv = up[5], ac = up[6];
        if (hp > 0.f) {
            int r = (int)(rf * 15.f);   // trunc toward zero == astype(int32)
            int c = (int)(cf * 15.f);
            int flat = r * 16 + c;
            if (team < 0.5f) {          // blue
                atomicAdd(&A[1][flat], 1.f);
                atomicAdd(&A[3][flat], hp);
                atomicAdd(&A[5][flat], mv);
                atomicAdd(&A[6][flat], ac);
            } else {                    // red
                atomicAdd(&A[2][flat], 1.f);
                atomicAdd(&A[4][flat], hp);
                atomicAdd(&A[7][flat], mv);
                atomicAdd(&A[8][flat], ac);
            }
        }
    }
    __syncthreads();

    const int quarter = tid >> 8;
    const int p = tid & 255;
    const int h = p >> 4, w = p & 15;
    const bool bN = h > 0, bS = h < 15, bW = w > 0, bE = w < 15;

    // conv1: 9 -> 32 (quarter computes 8 out-ch); write act1 to rows 32..63
    {
        const int o0 = quarter * 8;
        float acc[8];
        #pragma unroll
        for (int o = 0; o < 8; ++o) acc[o] = b1[o0 + o];
        for (int c = 0; c < 9; ++c) {
            float win[9];
            load_win(&A[c][0], p, bN, bS, bW, bE, win);
            #pragma unroll
            for (int o = 0; o < 8; ++o) {
                const float* wk = w1 + ((size_t)(o0 + o) * 9 + c) * 9;
                #pragma unroll
                for (int k = 0; k < 9; ++k) acc[o] = fmaf(win[k], wk[k], acc[o]);
            }
        }
        #pragma unroll
        for (int o = 0; o < 8; ++o) A[32 + o0 + o][p] = fmaxf(acc[o], 0.f);
    }
    __syncthreads();

    // conv2: 32 -> 64 (quarter computes 16 out-ch), reg-accumulate then overwrite
    {
        const int o0 = quarter * 16;
        float acc[16];
        #pragma unroll
        for (int o = 0; o < 16; ++o) acc[o] = b2[o0 + o];
        for (int c = 0; c < 32; ++c) {
            float win[9];
            load_win(&A[32 + c][0], p, bN, bS, bW, bE, win);
            #pragma unroll
            for (int o = 0; o < 16; ++o) {
                const float* wk = w2 + ((size_t)(o0 + o) * 32 + c) * 9;
                #pragma unroll
                for (int k = 0; k < 9; ++k) acc[o] = fmaf(win[k], wk[k], acc[o]);
            }
        }
        __syncthreads();   // all act1 reads complete
        #pragma unroll
        for (int o = 0; o < 16; ++o) A[o0 + o][p] = fmaxf(acc[o], 0.f);
    }
    __syncthreads();

    // conv3: 64 -> 64 (quarter computes 16 out-ch), reg-accumulate then overwrite
    {
        const int o0 = quarter * 16;
        float acc[16];
        #pragma unroll
        for (int o = 0; o < 16; ++o) acc[o] = b3[o0 + o];
        for (int c = 0; c < 64; ++c) {
            float win[9];
            load_win(&A[c][0], p, bN, bS, bW, bE, win);
            #pragma unroll
            for (int o = 0; o < 16; ++o) {
                const float* wk = w3 + ((size_t)(o0 + o) * 64 + c) * 9;
                #pragma unroll
                for (int k = 0; k < 9; ++k) acc[o] = fmaf(win[k], wk[k], acc[o]);
            }
        }
        __syncthreads();   // all act2 reads complete
        #pragma unroll
        for (int o = 0; o < 16; ++o) A[o0 + o][p] = fmaxf(acc[o], 0.f);
    }
    __syncthreads();

    // 4x4 avg pool -> pooled[b][ch*16 + ph*4 + pw]  (matches fc_w input order)
    {
        const int j = tid;            // 1024 outputs, 1024 threads
        const int ch = j >> 4, q = j & 15, ph = q >> 2, pw = q & 3;
        float s = 0.f;
        #pragma unroll
        for (int dy = 0; dy < 4; ++dy)
            #pragma unroll
            for (int dx = 0; dx < 4; ++dx)
                s += A[ch][(ph * 4 + dy) * 16 + (pw * 4 + dx)];
        pooled[(size_t)b * 1024 + j] = s * 0.0625f;
    }
}

// ---------------------------------------------------------------------------
// K2: tail MLP. 8 batch rows per block, 256 threads. Each thread owns one
// output column for all 8 rows (weight float4 reused 8x; x reads are LDS
// broadcasts).
// ---------------------------------------------------------------------------
__global__ __launch_bounds__(256) void tail_kernel(
    const float* __restrict__ obs,
    const float* __restrict__ pooled,
    const float* __restrict__ fcw, const float* __restrict__ fcb,
    const float* __restrict__ u1w, const float* __restrict__ u1b,
    const float* __restrict__ u2w, const float* __restrict__ u2b,
    const float* __restrict__ t1w, const float* __restrict__ t1b,
    const float* __restrict__ t2w, const float* __restrict__ t2b,
    const float* __restrict__ aw,  const float* __restrict__ ab,
    const float* __restrict__ cw,  const float* __restrict__ cb,
    float* __restrict__ out, int NB)
{
    __shared__ float xs[8][1024];   // pooled rows
    __shared__ float tc[8][320];    // concat(cnn_feat, unit_feat)
    __shared__ float h1[8][256];
    __shared__ float h2[8][256];
    __shared__ float uo[8][32];
    __shared__ float uh[8][64];

    const int tid = threadIdx.x;
    const int r0  = blockIdx.x * 8;

    // stage pooled rows (float4) + unit obs
    {
        const float4* src = (const float4*)(pooled + (size_t)r0 * 1024);
        float4* dst = (float4*)&xs[0][0];
        for (int i = tid; i < 2048; i += 256)
            if (r0 + (i >> 8) < NB) dst[i] = src[i];
    }
    {
        int r = tid >> 5, j = tid & 31;
        if (tid < 256 && r0 + r < NB)
            uo[r][j] = obs[(size_t)(r0 + r) * OBS_STRIDE + 458 + j];
    }
    __syncthreads();

    // u1: 32 -> 64
    for (int i = tid; i < 512; i += 256) {
        int r = i >> 6, o = i & 63;
        float a = u1b[o];
        const float* wr = u1w + o * 32;
        #pragma unroll
        for (int k = 0; k < 32; ++k) a = fmaf(uo[r][k], wr[k], a);
        uh[r][o] = fmaxf(a, 0.f);
    }
    __syncthreads();

    // u2: 64 -> 64 -> tc[r][256+o]
    for (int i = tid; i < 512; i += 256) {
        int r = i >> 6, o = i & 63;
        float a = u2b[o];
        const float* wr = u2w + o * 64;
        #pragma unroll
        for (int k = 0; k < 64; ++k) a = fmaf(uh[r][k], wr[k], a);
        tc[r][256 + o] = fmaxf(a, 0.f);
    }

    // fc: 1024 -> 256 (o = tid), into tc[r][0..255]
    {
        float acc[8] = {0, 0, 0, 0, 0, 0, 0, 0};
        const float4* wv = (const float4*)(fcw + (size_t)tid * 1024);
        for (int k4 = 0; k4 < 256; ++k4) {
            float4 w4 = wv[k4];
            #pragma unroll
            for (int r = 0; r < 8; ++r) {
                float4 x4 = *(const float4*)&xs[r][k4 << 2];
                acc[r] = fmaf(x4.x, w4.x, acc[r]);
                acc[r] = fmaf(x4.y, w4.y, acc[r]);
                acc[r] = fmaf(x4.z, w4.z, acc[r]);
                acc[r] = fmaf(x4.w, w4.w, acc[r]);
            }
        }
        float bb = fcb[tid];
        #pragma unroll
        for (int r = 0; r < 8; ++r) tc[r][tid] = fmaxf(acc[r] + bb, 0.f);
    }
    __syncthreads();

    // t1: 320 -> 256
    {
        float acc[8] = {0, 0, 0, 0, 0, 0, 0, 0};
        const float4* wv = (const float4*)(t1w + (size_t)tid * 320);
        for (int k4 = 0; k4 < 80; ++k4) {
            float4 w4 = wv[k4];
            #pragma unroll
            for (int r = 0; r < 8; ++r) {
                float4 x4 = *(const float4*)&tc[r][k4 << 2];
                acc[r] = fmaf(x4.x, w4.x, acc[r]);
                acc[r] = fmaf(x4.y, w4.y, acc[r]);
                acc[r] = fmaf(x4.z, w4.z, acc[r]);
                acc[r] = fmaf(x4.w, w4.w, acc[r]);
            }
        }
        float bb = t1b[tid];
        #pragma unroll
        for (int r = 0; r < 8; ++r) h1[r][tid] = fmaxf(acc[r] + bb, 0.f);
    }
    __syncthreads();

    // t2: 256 -> 256
    {
        float acc[8] = {0, 0, 0, 0, 0, 0, 0, 0};
        const float4* wv = (const float4*)(t2w + (size_t)tid * 256);
        for (int k4 = 0; k4 < 64; ++k4) {
            float4 w4 = wv[k4];
            #pragma unroll
            for (int r = 0; r < 8; ++r) {
                float4 x4 = *(const float4*)&h1[r][k4 << 2];
                acc[r] = fmaf(x4.x, w4.x, acc[r]);
                acc[r] = fmaf(x4.y, w4.y, acc[r]);
                acc[r] = fmaf(x4.z, w4.z, acc[r]);
                acc[r] = fmaf(x4.w, w4.w, acc[r]);
            }
        }
        float bb = t2b[tid];
        #pragma unroll
        for (int r = 0; r < 8; ++r) h2[r][tid] = fmaxf(acc[r] + bb, 0.f);
    }
    __syncthreads();

    // heads: actor (B,16) then critic (B,1), concatenated flat in d_out
    if (tid < 128) {
        int r = tid >> 4, a = tid & 15;
        if (r0 + r < NB) {
            float acc = ab[a];
            const float* wr = aw + a * 256;
            for (int k = 0; k < 256; ++k) acc = fmaf(h2[r][k], wr[k], acc);
            out[(size_t)(r0 + r) * 16 + a] = acc;
        }
    } else if (tid < 136) {
        int r = tid - 128;
        if (r0 + r < NB) {
            float acc = cb[0];
            for (int k = 0; k < 256; ++k) acc = fmaf(h2[r][k], cw[k], acc);
            out[(size_t)NB * 16 + (r0 + r)] = acc;
        }
    }
}

extern "C" void kernel_launch(void* const* d_in, const int* in_sizes, int n_in,
                              void* d_out, int out_size, void* d_ws, size_t ws_size,
                              hipStream_t stream)
{
    const float* obs = (const float*)d_in[0];
    const float* w1  = (const float*)d_in[1];
    const float* b1  = (const float*)d_in[2];
    const float* w2  = (const float*)d_in[3];
    const float* b2  = (const float*)d_in[4];
    const float* w3  = (const float*)d_in[5];
    const float* b3  = (const float*)d_in[6];
    const float* fcw = (const float*)d_in[7];
    const float* fcb = (const float*)d_in[8];
    const float* u1w = (const float*)d_in[9];
    const float* u1b = (const float*)d_in[10];
    const float* u2w = (const float*)d_in[11];
    const float* u2b = (const float*)d_in[12];
    const float* t1w = (const float*)d_in[13];
    const float* t1b = (const float*)d_in[14];
    const float* t2w = (const float*)d_in[15];
    const float* t2b = (const float*)d_in[16];
    const float* aw  = (const float*)d_in[17];
    const float* ab  = (const float*)d_in[18];
    const float* cw  = (const float*)d_in[19];
    const float* cb  = (const float*)d_in[20];

    const int NB = in_sizes[0] / OBS_STRIDE;      // 16384
    float* pooled = (float*)d_ws;                 // NB*1024 floats = 64 MB

    conv_kernel<<<NB, 1024, 0, stream>>>(obs, w1, b1, w2, b2, w3, b3, pooled);
    tail_kernel<<<(NB + 7) / 8, 256, 0, stream>>>(obs, pooled,
                                                  fcw, fcb, u1w, u1b, u2w, u2b,
                                                  t1w, t1b, t2w, t2b,
                                                  aw, ab, cw, cb,
                                                  (float*)d_out, NB);
}

// Round 3
// 908.747 us; speedup vs baseline: 28.6454x; 28.6454x over previous
//
#include <hip/hip_runtime.h>

#define OBS_STRIDE 490

typedef _Float16 half8 __attribute__((ext_vector_type(8)));
typedef _Float16 half4 __attribute__((ext_vector_type(4)));
typedef float f32x4 __attribute__((ext_vector_type(4)));

union H8 { half8 h; uint4 u; };

// ---------------------------------------------------------------------------
// prep_weights: reformat conv weights into MFMA A-fragments (f16, 16B/lane).
// Fragment table: conv1 [0,18): id = sh*2+mt   (KT=1, MT=2, C=9 zero-padded)
//                 conv2 [18,54): 18 + sh*4+mt  (KT=1, MT=4, C=32)
//                 conv3 [54,126): 54 + (sh*2+kt)*4+mt (KT=2, MT=4, C=64)
// Lane l supplies W[o = mt*16 + (l&15)][c = kt*32 + (l>>4)*8 + i], i=0..7.
// ---------------------------------------------------------------------------
__global__ __launch_bounds__(256) void prep_weights(
    const float* __restrict__ w1, const float* __restrict__ w2,
    const float* __restrict__ w3, uint4* __restrict__ wfrag)
{
    int gid = blockIdx.x * 256 + threadIdx.x;
    if (gid >= 126 * 64) return;
    int fid = gid >> 6, lane = gid & 63;
    const float* W; int C, sh, kt, mt;
    if (fid < 18)      { int f = fid;      W = w1; C = 9;  sh = f >> 1; kt = 0;            mt = f & 1; }
    else if (fid < 54) { int f = fid - 18; W = w2; C = 32; sh = f >> 2; kt = 0;            mt = f & 3; }
    else               { int f = fid - 54; W = w3; C = 64; sh = f >> 3; kt = (f >> 2) & 1; mt = f & 3; }
    int o  = mt * 16 + (lane & 15);
    int c0 = kt * 32 + ((lane >> 4) << 3);
    H8 v;
    #pragma unroll
    for (int i = 0; i < 8; ++i) {
        int c = c0 + i;
        float x = (c < C) ? W[(o * C + c) * 9 + sh] : 0.f;   // (O,I,3,3): sh = ky*3+kx
        v.h[i] = (_Float16)x;
    }
    wfrag[gid] = v.u;
}

// ---------------------------------------------------------------------------
// conv_kernel: one image per block, 256 threads (4 waves x 4 image-rows).
// LDS activation buffer: [ys 0..17][xs 0..17][c 0..63] f16, zero halo,
// 16B-chunk XOR swizzle: chunk' = chunk ^ (xs&7)  (kills the 128B-stride
// bank conflict on ds_read_b128 B-fragments).
// Each layer: 9 shifts x KT k-tiles of v_mfma_f32_16x16x32_f16, acc in regs
// (bias-initialized), then sync -> ReLU+f16 write in place -> sync.
// ---------------------------------------------------------------------------
template<int KT, int MT, int FRAG_BASE>
__device__ __forceinline__ void conv_layer(
    unsigned char* Abuf, const uint4* __restrict__ wfrag,
    const float* __restrict__ bias, int lane, int wv)
{
    const int x = lane & 15;
    const int q = lane >> 4;
    f32x4 acc[4][MT];
    #pragma unroll
    for (int mt = 0; mt < MT; ++mt) {
        f32x4 bv = *(const f32x4*)(bias + mt * 16 + q * 4);
        #pragma unroll
        for (int row = 0; row < 4; ++row) acc[row][mt] = bv;
    }
    #pragma unroll
    for (int sh = 0; sh < 9; ++sh) {
        const int dy = sh / 3 - 1, dx = sh % 3 - 1;
        const int xs = x + dx + 1;                 // 0..17
        #pragma unroll
        for (int kt = 0; kt < KT; ++kt) {
            H8 wf[MT];
            #pragma unroll
            for (int mt = 0; mt < MT; ++mt)
                wf[mt].u = wfrag[(FRAG_BASE + (sh * KT + kt) * MT + mt) * 64 + lane];
            const int chunk = ((kt * 4 + q) ^ (xs & 7)) << 4;
            #pragma unroll
            for (int row = 0; row < 4; ++row) {
                const int ys = wv * 4 + row + dy + 1;   // 0..17
                half8 bf = *(const half8*)(Abuf + ys * 2304 + xs * 128 + chunk);
                #pragma unroll
                for (int mt = 0; mt < MT; ++mt)
                    acc[row][mt] = __builtin_amdgcn_mfma_f32_16x16x32_f16(
                        wf[mt].h, bf, acc[row][mt], 0, 0, 0);
            }
        }
    }
    __syncthreads();
    const int xs1 = x + 1;
    #pragma unroll
    for (int row = 0; row < 4; ++row) {
        const int ys = wv * 4 + row + 1;
        #pragma unroll
        for (int mt = 0; mt < MT; ++mt) {
            half4 hv;
            #pragma unroll
            for (int r = 0; r < 4; ++r) hv[r] = (_Float16)fmaxf(acc[row][mt][r], 0.f);
            const int ob = mt * 32 + q * 8;            // byte offset of o0 in 128B row
            const int addr = ys * 2304 + xs1 * 128 + ((((ob >> 4) ^ (xs1 & 7))) << 4) + (ob & 15);
            *(half4*)(Abuf + addr) = hv;
        }
    }
    __syncthreads();
}

__global__ __launch_bounds__(256, 2) void conv_kernel(
    const float* __restrict__ obs,
    const uint4* __restrict__ wfrag,
    const float* __restrict__ b1, const float* __restrict__ b2,
    const float* __restrict__ b3,
    _Float16* __restrict__ pooled)
{
    __shared__ alignas(16) unsigned char Abuf[18 * 18 * 128];  // 41472 B
    __shared__ float G[8][256];                                 // 8192 B

    const int tid = threadIdx.x;
    const int b = blockIdx.x;
    const float* ob = obs + (size_t)b * OBS_STRIDE;

    // zero activation buffer (incl. halo) + scatter staging
    {
        uint4 z = {0, 0, 0, 0};
        uint4* A4 = (uint4*)Abuf;
        for (int i = tid; i < 2592; i += 256) A4[i] = z;
        float4 zf = {0.f, 0.f, 0.f, 0.f};
        float4* G4 = (float4*)G;
        for (int i = tid; i < 512; i += 256) G4[i] = zf;
    }
    __syncthreads();

    // unit scatter into fp32 staging (reference fp32 index math)
    if (tid < 20) {
        const float* up = ob + 256 + tid * 10;
        float team = up[1], rf = up[2], cf = up[3];
        float hp = up[4], mv = up[5], ac = up[6];
        if (hp > 0.f) {
            int r = (int)(rf * 15.f), c = (int)(cf * 15.f);
            int flat = r * 16 + c;
            if (team < 0.5f) {       // blue
                atomicAdd(&G[0][flat], 1.f);
                atomicAdd(&G[2][flat], hp);
                atomicAdd(&G[4][flat], mv);
                atomicAdd(&G[5][flat], ac);
            } else {                 // red
                atomicAdd(&G[1][flat], 1.f);
                atomicAdd(&G[3][flat], hp);
                atomicAdd(&G[6][flat], mv);
                atomicAdd(&G[7][flat], ac);
            }
        }
    }
    __syncthreads();

    // write 9 input channels (terrain + 8 scatter) to f16 buffer, swizzled
    {
        int p = tid & 255, xsg = (p & 15) + 1, ysg = (p >> 4) + 1;
        H8 v;
        v.h[0] = (_Float16)ob[p];
        #pragma unroll
        for (int c = 1; c < 8; ++c) v.h[c] = (_Float16)G[c - 1][p];
        *(uint4*)(Abuf + ysg * 2304 + xsg * 128 + ((xsg & 7) << 4)) = v.u;
        *(_Float16*)(Abuf + ysg * 2304 + xsg * 128 + ((1 ^ (xsg & 7)) << 4)) = (_Float16)G[7][p];
    }
    __syncthreads();

    const int lane = tid & 63, wv = tid >> 6;
    conv_layer<1, 2, 0 >(Abuf, wfrag, b1, lane, wv);   // 9(->32ch pad) -> 32
    conv_layer<1, 4, 18>(Abuf, wfrag, b2, lane, wv);   // 32 -> 64
    conv_layer<2, 4, 54>(Abuf, wfrag, b3, lane, wv);   // 64 -> 64

    // 4x4 avg pool -> pooled[b][ch*16 + ph*4 + pw] (f16)
    {
        int qq = tid & 15, cg = tid >> 4;   // qq: pool cell, cg: channel group
        int ph = qq >> 2, pw = qq & 3;
        int ch0 = cg * 4;
        float s[4] = {0.f, 0.f, 0.f, 0.f};
        int ob2 = ch0 * 2;
        #pragma unroll
        for (int dy = 0; dy < 4; ++dy) {
            int ys = ph * 4 + dy + 1;
            #pragma unroll
            for (int dx = 0; dx < 4; ++dx) {
                int xs = pw * 4 + dx + 1;
                int addr = ys * 2304 + xs * 128 + ((((ob2 >> 4) ^ (xs & 7))) << 4) + (ob2 & 15);
                half4 hv = *(const half4*)(Abuf + addr);
                #pragma unroll
                for (int cc = 0; cc < 4; ++cc) s[cc] += (float)hv[cc];
            }
        }
        _Float16* pb = pooled + (size_t)b * 1024;
        #pragma unroll
        for (int cc = 0; cc < 4; ++cc)
            pb[(ch0 + cc) * 16 + qq] = (_Float16)(s[cc] * 0.0625f);
    }
}

// ---------------------------------------------------------------------------
// tail_kernel: 8 batch rows per block, 256 threads; thread owns one output
// column for all 8 rows (weight float4 reused 8x, x reads LDS-broadcast).
// ---------------------------------------------------------------------------
__global__ __launch_bounds__(256) void tail_kernel(
    const float* __restrict__ obs,
    const _Float16* __restrict__ pooled,
    const float* __restrict__ fcw, const float* __restrict__ fcb,
    const float* __restrict__ u1w, const float* __restrict__ u1b,
    const float* __restrict__ u2w, const float* __restrict__ u2b,
    const float* __restrict__ t1w, const float* __restrict__ t1b,
    const float* __restrict__ t2w, const float* __restrict__ t2b,
    const float* __restrict__ aw,  const float* __restrict__ ab,
    const float* __restrict__ cw,  const float* __restrict__ cb,
    float* __restrict__ out, int NB)
{
    __shared__ float xs[8][1024];
    __shared__ float tc[8][320];
    __shared__ float h1[8][256];
    __shared__ float h2[8][256];
    __shared__ float uo[8][32];
    __shared__ float uh[8][64];

    const int tid = threadIdx.x;
    const int r0  = blockIdx.x * 8;

    // stage pooled rows (f16 -> f32) + unit obs
    {
        const half8* src = (const half8*)(pooled + (size_t)r0 * 1024);
        for (int i = tid; i < 1024; i += 256) {
            half8 v = src[i];
            int r = i >> 7, j = (i & 127) << 3;
            #pragma unroll
            for (int k = 0; k < 8; ++k) xs[r][j + k] = (float)v[k];
        }
    }
    {
        int r = tid >> 5, j = tid & 31;
        uo[r][j] = obs[(size_t)(r0 + r) * OBS_STRIDE + 458 + j];
    }
    __syncthreads();

    // u1: 32 -> 64
    for (int i = tid; i < 512; i += 256) {
        int r = i >> 6, o = i & 63;
        float a = u1b[o];
        const float* wr = u1w + o * 32;
        #pragma unroll
        for (int k = 0; k < 32; ++k) a = fmaf(uo[r][k], wr[k], a);
        uh[r][o] = fmaxf(a, 0.f);
    }
    __syncthreads();

    // u2: 64 -> 64 -> tc[r][256+o]
    for (int i = tid; i < 512; i += 256) {
        int r = i >> 6, o = i & 63;
        float a = u2b[o];
        const float* wr = u2w + o * 64;
        #pragma unroll
        for (int k = 0; k < 64; ++k) a = fmaf(uh[r][k], wr[k], a);
        tc[r][256 + o] = fmaxf(a, 0.f);
    }

    // fc: 1024 -> 256 (o = tid)
    {
        float acc[8] = {0, 0, 0, 0, 0, 0, 0, 0};
        const float4* wv = (const float4*)(fcw + (size_t)tid * 1024);
        for (int k4 = 0; k4 < 256; ++k4) {
            float4 w4 = wv[k4];
            #pragma unroll
            for (int r = 0; r < 8; ++r) {
                float4 x4 = *(const float4*)&xs[r][k4 << 2];
                acc[r] = fmaf(x4.x, w4.x, acc[r]);
                acc[r] = fmaf(x4.y, w4.y, acc[r]);
                acc[r] = fmaf(x4.z, w4.z, acc[r]);
                acc[r] = fmaf(x4.w, w4.w, acc[r]);
            }
        }
        float bb = fcb[tid];
        #pragma unroll
        for (int r = 0; r < 8; ++r) tc[r][tid] = fmaxf(acc[r] + bb, 0.f);
    }
    __syncthreads();

    // t1: 320 -> 256
    {
        float acc[8] = {0, 0, 0, 0, 0, 0, 0, 0};
        const float4* wv = (const float4*)(t1w + (size_t)tid * 320);
        for (int k4 = 0; k4 < 80; ++k4) {
            float4 w4 = wv[k4];
            #pragma unroll
            for (int r = 0; r < 8; ++r) {
                float4 x4 = *(const float4*)&tc[r][k4 << 2];
                acc[r] = fmaf(x4.x, w4.x, acc[r]);
                acc[r] = fmaf(x4.y, w4.y, acc[r]);
                acc[r] = fmaf(x4.z, w4.z, acc[r]);
                acc[r] = fmaf(x4.w, w4.w, acc[r]);
            }
        }
        float bb = t1b[tid];
        #pragma unroll
        for (int r = 0; r < 8; ++r) h1[r][tid] = fmaxf(acc[r] + bb, 0.f);
    }
    __syncthreads();

    // t2: 256 -> 256
    {
        float acc[8] = {0, 0, 0, 0, 0, 0, 0, 0};
        const float4* wv = (const float4*)(t2w + (size_t)tid * 256);
        for (int k4 = 0; k4 < 64; ++k4) {
            float4 w4 = wv[k4];
            #pragma unroll
            for (int r = 0; r < 8; ++r) {
                float4 x4 = *(const float4*)&h1[r][k4 << 2];
                acc[r] = fmaf(x4.x, w4.x, acc[r]);
                acc[r] = fmaf(x4.y, w4.y, acc[r]);
                acc[r] = fmaf(x4.z, w4.z, acc[r]);
                acc[r] = fmaf(x4.w, w4.w, acc[r]);
            }
        }
        float bb = t2b[tid];
        #pragma unroll
        for (int r = 0; r < 8; ++r) h2[r][tid] = fmaxf(acc[r] + bb, 0.f);
    }
    __syncthreads();

    // heads
    if (tid < 128) {
        int r = tid >> 4, a = tid & 15;
        float acc = ab[a];
        const float* wr = aw + a * 256;
        for (int k = 0; k < 256; ++k) acc = fmaf(h2[r][k], wr[k], acc);
        out[(size_t)(r0 + r) * 16 + a] = acc;
    } else if (tid < 136) {
        int r = tid - 128;
        float acc = cb[0];
        for (int k = 0; k < 256; ++k) acc = fmaf(h2[r][k], cw[k], acc);
        out[(size_t)NB * 16 + (r0 + r)] = acc;
    }
}

extern "C" void kernel_launch(void* const* d_in, const int* in_sizes, int n_in,
                              void* d_out, int out_size, void* d_ws, size_t ws_size,
                              hipStream_t stream)
{
    const float* obs = (const float*)d_in[0];
    const float* w1  = (const float*)d_in[1];
    const float* b1  = (const float*)d_in[2];
    const float* w2  = (const float*)d_in[3];
    const float* b2  = (const float*)d_in[4];
    const float* w3  = (const float*)d_in[5];
    const float* b3  = (const float*)d_in[6];
    const float* fcw = (const float*)d_in[7];
    const float* fcb = (const float*)d_in[8];
    const float* u1w = (const float*)d_in[9];
    const float* u1b = (const float*)d_in[10];
    const float* u2w = (const float*)d_in[11];
    const float* u2b = (const float*)d_in[12];
    const float* t1w = (const float*)d_in[13];
    const float* t1b = (const float*)d_in[14];
    const float* t2w = (const float*)d_in[15];
    const float* t2b = (const float*)d_in[16];
    const float* aw  = (const float*)d_in[17];
    const float* ab  = (const float*)d_in[18];
    const float* cw  = (const float*)d_in[19];
    const float* cb  = (const float*)d_in[20];

    const int NB = in_sizes[0] / OBS_STRIDE;           // 16384
    _Float16* pooled = (_Float16*)d_ws;                // NB*1024 f16 = 32 MB
    uint4* wfrag = (uint4*)((char*)d_ws + (size_t)NB * 1024 * 2);  // 126 KB

    prep_weights<<<32, 256, 0, stream>>>(w1, w2, w3, wfrag);
    conv_kernel<<<NB, 256, 0, stream>>>(obs, (const uint4*)wfrag, b1, b2, b3, pooled);
    tail_kernel<<<NB / 8, 256, 0, stream>>>(obs, pooled,
                                            fcw, fcb, u1w, u1b, u2w, u2b,
                                            t1w, t1b, t2w, t2b,
                                            aw, ab, cw, cb,
                                            (float*)d_out, NB);
}

// Round 5
// 550.531 us; speedup vs baseline: 47.2843x; 1.6507x over previous
//
#include <hip/hip_runtime.h>

#define OBS_STRIDE 490

typedef _Float16 half8 __attribute__((ext_vector_type(8)));
typedef _Float16 half4 __attribute__((ext_vector_type(4)));
typedef float f32x4 __attribute__((ext_vector_type(4)));

union H8 { half8 h; uint4 u; };

// Fragment table layout (uint4 per lane, 64 lanes per fragment):
//   conv1 [0,18)   conv2 [18,54)   conv3 [54,126)
//   fc   [126,638): 32 ksteps x 16 mt      (K=1024)
//   t1   [638,798): 10 ksteps x 16 mt      (K=320)
//   t2   [798,926):  8 ksteps x 16 mt      (K=256)
//   head [926,942):  8 ksteps x 2 mt       (K=256; mt0=actor, mt1 row0=critic)
#define FC_BASE 126
#define T1_BASE 638
#define T2_BASE 798
#define HD_BASE 926
#define NFRAG   942

__global__ __launch_bounds__(256) void prep_weights(
    const float* __restrict__ w1, const float* __restrict__ w2,
    const float* __restrict__ w3,
    const float* __restrict__ fcw, const float* __restrict__ t1w,
    const float* __restrict__ t2w,
    const float* __restrict__ aw,  const float* __restrict__ cw,
    uint4* __restrict__ wfrag)
{
    int gid = blockIdx.x * 256 + threadIdx.x;
    if (gid >= NFRAG * 64) return;
    int fid = gid >> 6, lane = gid & 63;
    H8 v;
    if (fid < 126) {
        const float* W; int C, sh, kt, mt;
        if (fid < 18)      { int f = fid;      W = w1; C = 9;  sh = f >> 1; kt = 0;            mt = f & 1; }
        else if (fid < 54) { int f = fid - 18; W = w2; C = 32; sh = f >> 2; kt = 0;            mt = f & 3; }
        else               { int f = fid - 54; W = w3; C = 64; sh = f >> 3; kt = (f >> 2) & 1; mt = f & 3; }
        int o  = mt * 16 + (lane & 15);
        int c0 = kt * 32 + ((lane >> 4) << 3);
        #pragma unroll
        for (int i = 0; i < 8; ++i) {
            int c = c0 + i;
            v.h[i] = (c < C) ? (_Float16)W[(o * C + c) * 9 + sh] : (_Float16)0.f;
        }
    } else {
        int o16 = lane & 15, k0 = (lane >> 4) << 3;
        if (fid < HD_BASE) {
            const float* W; int K, f;
            if (fid < T1_BASE)      { f = fid - FC_BASE; W = fcw; K = 1024; }
            else if (fid < T2_BASE) { f = fid - T1_BASE; W = t1w; K = 320;  }
            else                    { f = fid - T2_BASE; W = t2w; K = 256;  }
            int ks = f >> 4, mtg = f & 15;
            int o = mtg * 16 + o16;
            int kb = ks * 32 + k0;
            #pragma unroll
            for (int i = 0; i < 8; ++i)
                v.h[i] = (_Float16)W[(size_t)o * K + kb + i];
        } else {
            int f = fid - HD_BASE;
            int ks = f >> 1, mtg = f & 1;
            int kb = ks * 32 + k0;
            #pragma unroll
            for (int i = 0; i < 8; ++i) {
                float x;
                if (mtg == 0)      x = aw[o16 * 256 + kb + i];
                else if (o16 == 0) x = cw[kb + i];
                else               x = 0.f;
                v.h[i] = (_Float16)x;
            }
        }
    }
    wfrag[gid] = v.u;
}

// ---------------------------------------------------------------------------
// conv_kernel: UNCHANGED from round 3 (passed, ~380us).
// ---------------------------------------------------------------------------
template<int KT, int MT, int FRAG_BASE>
__device__ __forceinline__ void conv_layer(
    unsigned char* Abuf, const uint4* __restrict__ wfrag,
    const float* __restrict__ bias, int lane, int wv)
{
    const int x = lane & 15;
    const int q = lane >> 4;
    f32x4 acc[4][MT];
    #pragma unroll
    for (int mt = 0; mt < MT; ++mt) {
        f32x4 bv = *(const f32x4*)(bias + mt * 16 + q * 4);
        #pragma unroll
        for (int row = 0; row < 4; ++row) acc[row][mt] = bv;
    }
    #pragma unroll
    for (int sh = 0; sh < 9; ++sh) {
        const int dy = sh / 3 - 1, dx = sh % 3 - 1;
        const int xs = x + dx + 1;
        #pragma unroll
        for (int kt = 0; kt < KT; ++kt) {
            H8 wf[MT];
            #pragma unroll
            for (int mt = 0; mt < MT; ++mt)
                wf[mt].u = wfrag[(FRAG_BASE + (sh * KT + kt) * MT + mt) * 64 + lane];
            const int chunk = ((kt * 4 + q) ^ (xs & 7)) << 4;
            #pragma unroll
            for (int row = 0; row < 4; ++row) {
                const int ys = wv * 4 + row + dy + 1;
                half8 bf = *(const half8*)(Abuf + ys * 2304 + xs * 128 + chunk);
                #pragma unroll
                for (int mt = 0; mt < MT; ++mt)
                    acc[row][mt] = __builtin_amdgcn_mfma_f32_16x16x32_f16(
                        wf[mt].h, bf, acc[row][mt], 0, 0, 0);
            }
        }
    }
    __syncthreads();
    const int xs1 = x + 1;
    #pragma unroll
    for (int row = 0; row < 4; ++row) {
        const int ys = wv * 4 + row + 1;
        #pragma unroll
        for (int mt = 0; mt < MT; ++mt) {
            half4 hv;
            #pragma unroll
            for (int r = 0; r < 4; ++r) hv[r] = (_Float16)fmaxf(acc[row][mt][r], 0.f);
            const int ob = mt * 32 + q * 8;
            const int addr = ys * 2304 + xs1 * 128 + ((((ob >> 4) ^ (xs1 & 7))) << 4) + (ob & 15);
            *(half4*)(Abuf + addr) = hv;
        }
    }
    __syncthreads();
}

__global__ __launch_bounds__(256, 2) void conv_kernel(
    const float* __restrict__ obs,
    const uint4* __restrict__ wfrag,
    const float* __restrict__ b1, const float* __restrict__ b2,
    const float* __restrict__ b3,
    _Float16* __restrict__ pooled)
{
    __shared__ alignas(16) unsigned char Abuf[18 * 18 * 128];
    __shared__ float G[8][256];

    const int tid = threadIdx.x;
    const int b = blockIdx.x;
    const float* ob = obs + (size_t)b * OBS_STRIDE;

    {
        uint4 z = {0, 0, 0, 0};
        uint4* A4 = (uint4*)Abuf;
        for (int i = tid; i < 2592; i += 256) A4[i] = z;
        float4 zf = {0.f, 0.f, 0.f, 0.f};
        float4* G4 = (float4*)G;
        for (int i = tid; i < 512; i += 256) G4[i] = zf;
    }
    __syncthreads();

    if (tid < 20) {
        const float* up = ob + 256 + tid * 10;
        float team = up[1], rf = up[2], cf = up[3];
        float hp = up[4], mv = up[5], ac = up[6];
        if (hp > 0.f) {
            int r = (int)(rf * 15.f), c = (int)(cf * 15.f);
            int flat = r * 16 + c;
            if (team < 0.5f) {
                atomicAdd(&G[0][flat], 1.f);
                atomicAdd(&G[2][flat], hp);
                atomicAdd(&G[4][flat], mv);
                atomicAdd(&G[5][flat], ac);
            } else {
                atomicAdd(&G[1][flat], 1.f);
                atomicAdd(&G[3][flat], hp);
                atomicAdd(&G[6][flat], mv);
                atomicAdd(&G[7][flat], ac);
            }
        }
    }
    __syncthreads();

    {
        int p = tid & 255, xsg = (p & 15) + 1, ysg = (p >> 4) + 1;
        H8 v;
        v.h[0] = (_Float16)ob[p];
        #pragma unroll
        for (int c = 1; c < 8; ++c) v.h[c] = (_Float16)G[c - 1][p];
        *(uint4*)(Abuf + ysg * 2304 + xsg * 128 + ((xsg & 7) << 4)) = v.u;
        *(_Float16*)(Abuf + ysg * 2304 + xsg * 128 + ((1 ^ (xsg & 7)) << 4)) = (_Float16)G[7][p];
    }
    __syncthreads();

    const int lane = tid & 63, wv = tid >> 6;
    conv_layer<1, 2, 0 >(Abuf, wfrag, b1, lane, wv);
    conv_layer<1, 4, 18>(Abuf, wfrag, b2, lane, wv);
    conv_layer<2, 4, 54>(Abuf, wfrag, b3, lane, wv);

    {
        int qq = tid & 15, cg = tid >> 4;
        int ph = qq >> 2, pw = qq & 3;
        int ch0 = cg * 4;
        float s[4] = {0.f, 0.f, 0.f, 0.f};
        int ob2 = ch0 * 2;
        #pragma unroll
        for (int dy = 0; dy < 4; ++dy) {
            int ys = ph * 4 + dy + 1;
            #pragma unroll
            for (int dx = 0; dx < 4; ++dx) {
                int xs = pw * 4 + dx + 1;
                int addr = ys * 2304 + xs * 128 + ((((ob2 >> 4) ^ (xs & 7))) << 4) + (ob2 & 15);
                half4 hv = *(const half4*)(Abuf + addr);
                #pragma unroll
                for (int cc = 0; cc < 4; ++cc) s[cc] += (float)hv[cc];
            }
        }
        _Float16* pb = pooled + (size_t)b * 1024;
        #pragma unroll
        for (int cc = 0; cc < 4; ++cc)
            pb[(ch0 + cc) * 16 + qq] = (_Float16)(s[cc] * 0.0625f);
    }
}

// ---------------------------------------------------------------------------
// tail_kernel v2 (MFMA): 32 batch rows/block, 256 threads = 4 waves.
// Wave w owns output features [w*64, w*64+64) as 4 M-tiles, over 2 batch
// groups of 16. Activations transposed in LDS tcT[n][k] f16 (stride 344 ->
// 688B -> 2-way bank aliasing = free), reused in place per layer with
// read-all -> sync -> write -> sync. fc B-fragments come straight from
// global `pooled` (lanes l,l+16,l+32,l+48 cover one 64B line per row).
// ---------------------------------------------------------------------------
__global__ __launch_bounds__(256) void tail_kernel(
    const float* __restrict__ obs,
    const _Float16* __restrict__ pooled,
    const uint4* __restrict__ wfrag,
    const float* __restrict__ fcb,
    const float* __restrict__ u1w, const float* __restrict__ u1b,
    const float* __restrict__ u2w, const float* __restrict__ u2b,
    const float* __restrict__ t1b, const float* __restrict__ t2b,
    const float* __restrict__ ab,  const float* __restrict__ cb,
    float* __restrict__ out, int NB)
{
    __shared__ alignas(16) _Float16 tcT[32][344];   // 22016 B
    __shared__ alignas(16) _Float16 uh[32][72];     //  4608 B

    const int tid  = threadIdx.x;
    const int lane = tid & 63, w = tid >> 6;
    const int nl   = lane & 15, q = lane >> 4;
    const int r0   = blockIdx.x * 32;

    // ---- unit MLP u1 (scalar): 32 rows x 8 threads each ----
    {
        const int r = tid >> 3, t8 = tid & 7;
        const float* up = obs + (size_t)(r0 + r) * OBS_STRIDE + 458;
        float xin[32];
        #pragma unroll
        for (int k2 = 0; k2 < 16; ++k2) {          // 8B-aligned float2 loads
            float2 v = *(const float2*)(up + k2 * 2);
            xin[k2 * 2] = v.x; xin[k2 * 2 + 1] = v.y;
        }
        #pragma unroll
        for (int oo = 0; oo < 8; ++oo) {
            int o = t8 * 8 + oo;
            float a = u1b[o];
            const float* wr = u1w + o * 32;
            #pragma unroll
            for (int k = 0; k < 32; ++k) a = fmaf(xin[k], wr[k], a);
            uh[r][o] = (_Float16)fmaxf(a, 0.f);
        }
    }
    __syncthreads();

    // ---- u2 -> tcT[:, 256..319] ----
    {
        const int r = tid >> 3, t8 = tid & 7;
        float xin[64];
        #pragma unroll
        for (int k8 = 0; k8 < 8; ++k8) {
            half8 v = *(const half8*)&uh[r][k8 * 8];
            #pragma unroll
            for (int j = 0; j < 8; ++j) xin[k8 * 8 + j] = (float)v[j];
        }
        #pragma unroll
        for (int oo = 0; oo < 8; ++oo) {
            int o = t8 * 8 + oo;
            float a = u2b[o];
            const float* wr = u2w + o * 64;
            #pragma unroll
            for (int k = 0; k < 64; ++k) a = fmaf(xin[k], wr[k], a);
            tcT[r][256 + o] = (_Float16)fmaxf(a, 0.f);
        }
    }

    // ---- fc: K=1024, 32 ksteps, B-frags direct from global pooled ----
    {
        f32x4 acc[4][2];
        #pragma unroll
        for (int mt = 0; mt < 4; ++mt) {
            f32x4 bv = *(const f32x4*)(fcb + (w * 4 + mt) * 16 + q * 4);
            acc[mt][0] = bv; acc[mt][1] = bv;
        }
        for (int ks = 0; ks < 32; ++ks) {
            H8 bf[2];
            #pragma unroll
            for (int g = 0; g < 2; ++g)
                bf[g].u = *(const uint4*)(pooled + (size_t)(r0 + g * 16 + nl) * 1024 + ks * 32 + q * 8);
            #pragma unroll
            for (int mt = 0; mt < 4; ++mt) {
                H8 af; af.u = wfrag[(size_t)(FC_BASE + ks * 16 + w * 4 + mt) * 64 + lane];
                #pragma unroll
                for (int g = 0; g < 2; ++g)
                    acc[mt][g] = __builtin_amdgcn_mfma_f32_16x16x32_f16(af.h, bf[g].h, acc[mt][g], 0, 0, 0);
            }
        }
        #pragma unroll
        for (int mt = 0; mt < 4; ++mt)
            #pragma unroll
            for (int g = 0; g < 2; ++g) {
                half4 hv;
                #pragma unroll
                for (int r = 0; r < 4; ++r) hv[r] = (_Float16)fmaxf(acc[mt][g][r], 0.f);
                *(half4*)&tcT[g * 16 + nl][(w * 4 + mt) * 16 + q * 4] = hv;
            }
    }
    __syncthreads();

    // ---- t1: K=320, 10 ksteps, B from tcT; in-place overwrite ----
    {
        f32x4 acc[4][2];
        #pragma unroll
        for (int mt = 0; mt < 4; ++mt) {
            f32x4 bv = *(const f32x4*)(t1b + (w * 4 + mt) * 16 + q * 4);
            acc[mt][0] = bv; acc[mt][1] = bv;
        }
        for (int ks = 0; ks < 10; ++ks) {
            H8 bf[2];
            #pragma unroll
            for (int g = 0; g < 2; ++g)
                bf[g].h = *(const half8*)&tcT[g * 16 + nl][ks * 32 + q * 8];
            #pragma unroll
            for (int mt = 0; mt < 4; ++mt) {
                H8 af; af.u = wfrag[(size_t)(T1_BASE + ks * 16 + w * 4 + mt) * 64 + lane];
                #pragma unroll
                for (int g = 0; g < 2; ++g)
                    acc[mt][g] = __builtin_amdgcn_mfma_f32_16x16x32_f16(af.h, bf[g].h, acc[mt][g], 0, 0, 0);
            }
        }
        __syncthreads();      // all tcT reads done before overwrite
        #pragma unroll
        for (int mt = 0; mt < 4; ++mt)
            #pragma unroll
            for (int g = 0; g < 2; ++g) {
                half4 hv;
                #pragma unroll
                for (int r = 0; r < 4; ++r) hv[r] = (_Float16)fmaxf(acc[mt][g][r], 0.f);
                *(half4*)&tcT[g * 16 + nl][(w * 4 + mt) * 16 + q * 4] = hv;
            }
    }
    __syncthreads();

    // ---- t2: K=256, 8 ksteps ----
    {
        f32x4 acc[4][2];
        #pragma unroll
        for (int mt = 0; mt < 4; ++mt) {
            f32x4 bv = *(const f32x4*)(t2b + (w * 4 + mt) * 16 + q * 4);
            acc[mt][0] = bv; acc[mt][1] = bv;
        }
        for (int ks = 0; ks < 8; ++ks) {
            H8 bf[2];
            #pragma unroll
            for (int g = 0; g < 2; ++g)
                bf[g].h = *(const half8*)&tcT[g * 16 + nl][ks * 32 + q * 8];
            #pragma unroll
            for (int mt = 0; mt < 4; ++mt) {
                H8 af; af.u = wfrag[(size_t)(T2_BASE + ks * 16 + w * 4 + mt) * 64 + lane];
                #pragma unroll
                for (int g = 0; g < 2; ++g)
                    acc[mt][g] = __builtin_amdgcn_mfma_f32_16x16x32_f16(af.h, bf[g].h, acc[mt][g], 0, 0, 0);
            }
        }
        __syncthreads();
        #pragma unroll
        for (int mt = 0; mt < 4; ++mt)
            #pragma unroll
            for (int g = 0; g < 2; ++g) {
                half4 hv;
                #pragma unroll
                for (int r = 0; r < 4; ++r) hv[r] = (_Float16)fmaxf(acc[mt][g][r], 0.f);
                *(half4*)&tcT[g * 16 + nl][(w * 4 + mt) * 16 + q * 4] = hv;
            }
    }
    __syncthreads();

    // ---- heads: K=256, 8 ksteps; wave0 = actor (16 rows), wave1 = critic ----
    if (w < 2) {
        f32x4 acc[2];
        if (w == 0) {
            f32x4 bv = *(const f32x4*)(ab + q * 4);
            acc[0] = bv; acc[1] = bv;
        } else {
            f32x4 bv = {0.f, 0.f, 0.f, 0.f};
            if (q == 0) bv[0] = cb[0];
            acc[0] = bv; acc[1] = bv;
        }
        for (int ks = 0; ks < 8; ++ks) {
            H8 af; af.u = wfrag[(size_t)(HD_BASE + ks * 2 + w) * 64 + lane];
            #pragma unroll
            for (int g = 0; g < 2; ++g) {
                half8 bf = *(const half8*)&tcT[g * 16 + nl][ks * 32 + q * 8];
                acc[g] = __builtin_amdgcn_mfma_f32_16x16x32_f16(af.h, bf, acc[g], 0, 0, 0);
            }
        }
        if (w == 0) {
            #pragma unroll
            for (int g = 0; g < 2; ++g) {
                float4 o4 = {acc[g][0], acc[g][1], acc[g][2], acc[g][3]};
                *(float4*)(out + (size_t)(r0 + g * 16 + nl) * 16 + q * 4) = o4;
            }
        } else if (q == 0) {
            #pragma unroll
            for (int g = 0; g < 2; ++g)
                out[(size_t)NB * 16 + r0 + g * 16 + nl] = acc[g][0];
        }
    }
}

extern "C" void kernel_launch(void* const* d_in, const int* in_sizes, int n_in,
                              void* d_out, int out_size, void* d_ws, size_t ws_size,
                              hipStream_t stream)
{
    const float* obs = (const float*)d_in[0];
    const float* w1  = (const float*)d_in[1];
    const float* b1  = (const float*)d_in[2];
    const float* w2  = (const float*)d_in[3];
    const float* b2  = (const float*)d_in[4];
    const float* w3  = (const float*)d_in[5];
    const float* b3  = (const float*)d_in[6];
    const float* fcw = (const float*)d_in[7];
    const float* fcb = (const float*)d_in[8];
    const float* u1w = (const float*)d_in[9];
    const float* u1b = (const float*)d_in[10];
    const float* u2w = (const float*)d_in[11];
    const float* u2b = (const float*)d_in[12];
    const float* t1w = (const float*)d_in[13];
    const float* t1b = (const float*)d_in[14];
    const float* t2w = (const float*)d_in[15];
    const float* t2b = (const float*)d_in[16];
    const float* aw  = (const float*)d_in[17];
    const float* ab  = (const float*)d_in[18];
    const float* cw  = (const float*)d_in[19];
    const float* cb  = (const float*)d_in[20];

    const int NB = in_sizes[0] / OBS_STRIDE;                       // 16384
    _Float16* pooled = (_Float16*)d_ws;                            // 32 MB
    uint4* wfrag = (uint4*)((char*)d_ws + (size_t)NB * 1024 * 2);  // 942 KB

    prep_weights<<<(NFRAG * 64 + 255) / 256, 256, 0, stream>>>(
        w1, w2, w3, fcw, t1w, t2w, aw, cw, wfrag);
    conv_kernel<<<NB, 256, 0, stream>>>(obs, (const uint4*)wfrag, b1, b2, b3, pooled);
    tail_kernel<<<NB / 32, 256, 0, stream>>>(obs, pooled, (const uint4*)wfrag,
                                             fcb, u1w, u1b, u2w, u2b,
                                             t1b, t2b, ab, cb,
                                             (float*)d_out, NB);
}